// Round 33
// baseline (478.585 us; speedup 1.0000x reference)
//
#include <hip/hip_runtime.h>
#include <math.h>

#define TT 16384      // B*S tokens
#define DD 2048       // hidden dim
#define EE 64         // experts
#define KTOP 8
#define BM 32         // rows per block (was 64 -> grid 512 = 2 blocks/CU)
#define BK 32         // k-chunk
#define NT (DD / BK)  // 64 k-tiles
#define SL 4096       // seq len
#define BB 4          // batch
#define XS_STR 36     // X-tile stride (32 + 4 pad)
#define WS_STR 68     // W-tile stride (64 + 4 pad)
#define LS_STR 68     // logits stride

// numpy SIMD float32 exp (P/Q rational — locked by R26/R27)
__device__ __forceinline__ float np_expf(float x) {
    const float LOG2E = 1.442695040888963407359924681001892137f;
    const float MAGIC = 0x1.800000p+23f;
    const float C1 = -6.93145752e-1f;
    const float C2 = -1.42860677e-6f;
    float q = __fmul_rn(x, LOG2E);
    q = __fadd_rn(q, MAGIC);
    q = __fsub_rn(q, MAGIC);
    x = __fmaf_rn(q, C1, x);
    x = __fmaf_rn(q, C2, x);
    float num = __fmaf_rn(5.082762527590693718096e-04f, x, 6.757896990527504603057e-03f);
    num = __fmaf_rn(num, x, 5.114512081637298353406e-02f);
    num = __fmaf_rn(num, x, 2.473615434895520810817e-01f);
    num = __fmaf_rn(num, x, 7.257664613233124478488e-01f);
    num = __fmaf_rn(num, x, 9.999999999980870924916e-01f);
    float den = __fmaf_rn(2.159509375685829852307e-02f, x, -2.742335390411667452936e-01f);
    den = __fmaf_rn(den, x, 1.0f);
    const float quot = __fdiv_rn(num, den);
    const int qi = (int)q;
    const float sc = __uint_as_float((unsigned int)(127 + qi) << 23);
    return __fmul_rn(quot, sc);
}

// GEMM arithmetic (LOCKED, bit-exact vs np ref): OpenBLAS skylakex sgemm,
// K=2048 -> chunks [320 x5, 224, 224], fold boundaries kt+1 in
// {10,20,30,40,50,57,64}; microkernel = 2 accumulator banks, QUADS
// assignment bank=(k>>2)&1 (unroll-8 pipeline), TREE combine (c0+c1),
// one f32 add into C per chunk.
__device__ __forceinline__ bool is_fold(int kt1) {
    return kt1 == 10 || kt1 == 20 || kt1 == 30 || kt1 == 40 ||
           kt1 == 50 || kt1 == 57 || kt1 == 64;
}

__global__ __launch_bounds__(256) void moe_gate_main(
    const float* __restrict__ X, const float* __restrict__ W,
    float* __restrict__ out, float* __restrict__ ws_cnt, float* __restrict__ ws_ssum)
{
    // stage buffers dead by epilogue -> union with logits tile
    __shared__ union {
        struct { float Xs[2][BK * XS_STR]; float Wsh[2][BK * WS_STR]; } st; // 26.6 KB
        struct { float L[BM * LS_STR]; } ep;                                 // 8.7 KB
    } sh;
    __shared__ float cnt[EE];

    const int tid  = threadIdx.x;
    const int row0 = blockIdx.x * BM;
    const int tr   = tid >> 4;   // 0..15 -> rows 2tr, 2tr+1
    const int tc   = tid & 15;   // 0..15 -> cols 4tc..4tc+3

    float tot[2][4];      // C across K-chunks
    float ch[2][2][4];    // 2 banks x (2 rows x 4 cols)
#pragma unroll
    for (int i = 0; i < 2; ++i)
#pragma unroll
        for (int j = 0; j < 4; ++j) {
            tot[i][j] = 0.f; ch[0][i][j] = 0.f; ch[1][i][j] = 0.f;
        }

    if (tid < EE) cnt[tid] = 0.f;

    // hoisted per-thread staging pointers + LDS destinations
    const float* xptr[4]; int xdst[4];
#pragma unroll
    for (int j = 0; j < 4; ++j) {              // X tile: 32r x 32k = 4/thread
        const int el = j * 256 + tid;
        const int r = el >> 5, kk = el & 31;
        xptr[j] = X + (size_t)(row0 + r) * DD + kk;
        xdst[j] = kk * XS_STR + r;
    }
    const float* wptr[8]; int wdst[8];
#pragma unroll
    for (int j = 0; j < 8; ++j) {              // W tile: 64r x 32k = 8/thread
        const int el = j * 256 + tid;
        const int r = el >> 5, kk = el & 31;
        wptr[j] = W + (size_t)r * DD + kk;
        wdst[j] = kk * WS_STR + r;
    }

    float xr[4], wr[8];
#pragma unroll
    for (int j = 0; j < 4; ++j) { xr[j] = *xptr[j]; xptr[j] += BK; }
#pragma unroll
    for (int j = 0; j < 8; ++j) { wr[j] = *wptr[j]; wptr[j] += BK; }
#pragma unroll
    for (int j = 0; j < 4; ++j) sh.st.Xs[0][xdst[j]] = xr[j];
#pragma unroll
    for (int j = 0; j < 8; ++j) sh.st.Wsh[0][wdst[j]] = wr[j];

    for (int kt = 0; kt < NT; ++kt) {
        __syncthreads();
        const int cur = kt & 1;
        if (kt + 1 < NT) {   // issue next-tile loads early (latency hides)
#pragma unroll
            for (int j = 0; j < 4; ++j) { xr[j] = *xptr[j]; xptr[j] += BK; }
#pragma unroll
            for (int j = 0; j < 8; ++j) { wr[j] = *wptr[j]; wptr[j] += BK; }
        }
        // 2-bank QUADS FMA chains; (kk>>2)&1 compile-time after unroll
#pragma unroll
        for (int kk = 0; kk < BK; ++kk) {
            const int p = (kk >> 2) & 1;
            const float2 a = *(const float2*)&sh.st.Xs[cur][kk * XS_STR + 2 * tr];
            const float4 b = *(const float4*)&sh.st.Wsh[cur][kk * WS_STR + 4 * tc];
            ch[p][0][0] = __fmaf_rn(a.x, b.x, ch[p][0][0]);
            ch[p][0][1] = __fmaf_rn(a.x, b.y, ch[p][0][1]);
            ch[p][0][2] = __fmaf_rn(a.x, b.z, ch[p][0][2]);
            ch[p][0][3] = __fmaf_rn(a.x, b.w, ch[p][0][3]);
            ch[p][1][0] = __fmaf_rn(a.y, b.x, ch[p][1][0]);
            ch[p][1][1] = __fmaf_rn(a.y, b.y, ch[p][1][1]);
            ch[p][1][2] = __fmaf_rn(a.y, b.z, ch[p][1][2]);
            ch[p][1][3] = __fmaf_rn(a.y, b.w, ch[p][1][3]);
        }
        if (is_fold(kt + 1)) {
#pragma unroll
            for (int i = 0; i < 2; ++i)
#pragma unroll
                for (int j = 0; j < 4; ++j) {
                    const float c2 = __fadd_rn(ch[0][i][j], ch[1][i][j]);
                    tot[i][j] = __fadd_rn(tot[i][j], c2);
                    ch[0][i][j] = 0.f; ch[1][i][j] = 0.f;
                }
        }
        if (kt + 1 < NT) {
#pragma unroll
            for (int j = 0; j < 4; ++j) sh.st.Xs[cur ^ 1][xdst[j]] = xr[j];
#pragma unroll
            for (int j = 0; j < 8; ++j) sh.st.Wsh[cur ^ 1][wdst[j]] = wr[j];
        }
    }

    __syncthreads();   // all stage reads done before union reuse
#pragma unroll
    for (int i = 0; i < 2; ++i) {
        float4 v; v.x = tot[i][0]; v.y = tot[i][1]; v.z = tot[i][2]; v.w = tot[i][3];
        *(float4*)&sh.ep.L[(2 * tr + i) * LS_STR + 4 * tc] = v;
    }
    __syncthreads();

    if (tid < BM) {
        const int r = tid;
        float l[EE];
#pragma unroll
        for (int q = 0; q < 16; ++q) {
            const float4 v = *(const float4*)&sh.ep.L[r * LS_STR + 4 * q];
            l[4 * q] = v.x; l[4 * q + 1] = v.y; l[4 * q + 2] = v.z; l[4 * q + 3] = v.w;
        }
        float m = l[0];
#pragma unroll
        for (int e = 1; e < EE; ++e) m = fmaxf(m, l[e]);

        // u = np.exp(l - m) (P/Q rational)
        float u[EE];
#pragma unroll
        for (int e = 0; e < EE; ++e) u[e] = np_expf(__fsub_rn(l[e], m));

        // z = numpy pairwise (8 accumulators, ascending chunks,
        // ((r0+r1)+(r2+r3)) + ((r4+r5)+(r6+r7)))
        float rr[8];
#pragma unroll
        for (int j = 0; j < 8; ++j) rr[j] = u[j];
#pragma unroll
        for (int c = 1; c < 8; ++c)
#pragma unroll
            for (int j = 0; j < 8; ++j) rr[j] = __fadd_rn(rr[j], u[8 * c + j]);
        const float z = __fadd_rn(
            __fadd_rn(__fadd_rn(rr[0], rr[1]), __fadd_rn(rr[2], rr[3])),
            __fadd_rn(__fadd_rn(rr[4], rr[5]), __fadd_rn(rr[6], rr[7])));

        float s[EE];
#pragma unroll
        for (int e = 0; e < EE; ++e) s[e] = __fdiv_rn(u[e], z);

        // top-8 on f32 scores: value desc, index ASC on exact ties
        float pv = 3.4e38f; int pi = -1;
        float wk[KTOP]; int ti[KTOP]; float wsum = 0.f;
#pragma unroll
        for (int k = 0; k < KTOP; ++k) {
            float best = -3.4e38f; int bi = 0;
#pragma unroll
            for (int e = 0; e < EE; ++e) {
                const bool elig   = (s[e] < pv) || ((s[e] == pv) && (e > pi));
                const bool better = elig && (s[e] > best);
                best = better ? s[e] : best;
                bi   = better ? e    : bi;
            }
            wk[k] = best; ti[k] = bi; wsum = __fadd_rn(wsum, best);
            pv = best; pi = bi;
        }
        const float den = __fadd_rn(wsum, 1e-20f);

        const size_t t = (size_t)row0 + r;
        float4 o0, o1;
        o0.x = (float)ti[0]; o0.y = (float)ti[1]; o0.z = (float)ti[2]; o0.w = (float)ti[3];
        o1.x = (float)ti[4]; o1.y = (float)ti[5]; o1.z = (float)ti[6]; o1.w = (float)ti[7];
        *(float4*)&out[t * 8]     = o0;
        *(float4*)&out[t * 8 + 4] = o1;
        float* outw = out + (size_t)TT * KTOP;
        o0.x = __fdiv_rn(wk[0], den); o0.y = __fdiv_rn(wk[1], den);
        o0.z = __fdiv_rn(wk[2], den); o0.w = __fdiv_rn(wk[3], den);
        o1.x = __fdiv_rn(wk[4], den); o1.y = __fdiv_rn(wk[5], den);
        o1.z = __fdiv_rn(wk[6], den); o1.w = __fdiv_rn(wk[7], den);
        *(float4*)&outw[t * 8]     = o0;
        *(float4*)&outw[t * 8 + 4] = o1;

#pragma unroll
        for (int k = 0; k < KTOP; ++k) atomicAdd(&cnt[ti[k]], 1.f);

        // scores back to LDS for column sums
#pragma unroll
        for (int q = 0; q < 16; ++q) {
            float4 v;
            v.x = s[4 * q]; v.y = s[4 * q + 1]; v.z = s[4 * q + 2]; v.w = s[4 * q + 3];
            *(float4*)&sh.ep.L[r * LS_STR + 4 * q] = v;
        }
    }
    __syncthreads();

    if (tid < EE) {
        const int e = tid;
        float cs = 0.f;
#pragma unroll
        for (int r2 = 0; r2 < BM; ++r2) cs += sh.ep.L[r2 * LS_STR + e];
        const int b = row0 / SL;
        atomicAdd(&ws_ssum[b * EE + e], cs);
        atomicAdd(&ws_cnt[b * EE + e], cnt[e]);
    }
}

__global__ void moe_gate_aux(const float* __restrict__ ws_cnt,
                             const float* __restrict__ ws_ssum,
                             float* __restrict__ out_aux)
{
    __shared__ float red[4];
    const int tid = threadIdx.x;  // 256 = B*E cells
    float v = ws_cnt[tid] * ws_ssum[tid];
#pragma unroll
    for (int m = 32; m; m >>= 1) v += __shfl_xor(v, m, 64);
    if ((tid & 63) == 0) red[tid >> 6] = v;
    __syncthreads();
    if (tid == 0) {
        const float tot = red[0] + red[1] + red[2] + red[3];
        // aux = ALPHA * (1/B) * sum_{b,e} (cnt/(S*K/E)) * (ssum/S)
        out_aux[0] = tot * (1e-3f / ((float)BB * 512.f * (float)SL));
    }
}

extern "C" void kernel_launch(void* const* d_in, const int* in_sizes, int n_in,
                              void* d_out, int out_size, void* d_ws, size_t ws_size,
                              hipStream_t stream)
{
    const float* X = (const float*)d_in[0];
    const float* W = (const float*)d_in[1];
    float* out  = (float*)d_out;
    float* cnt  = (float*)d_ws;
    float* ssum = cnt + BB * EE;
    hipMemsetAsync(d_ws, 0, 2 * BB * EE * sizeof(float), stream);
    moe_gate_main<<<TT / BM, 256, 0, stream>>>(X, W, out, cnt, ssum);
    moe_gate_aux<<<1, 256, 0, stream>>>(cnt, ssum, out + (size_t)2 * TT * KTOP);
}

// Round 34
// 227.623 us; speedup vs baseline: 2.1025x; 2.1025x over previous
//
#include <hip/hip_runtime.h>
#include <math.h>

#define TT 16384      // B*S tokens
#define DD 2048       // hidden dim
#define EE 64         // experts
#define KTOP 8
#define BM 64         // rows per block (grid 256 = 1 block/CU)
#define BK 32         // k-chunk
#define NT (DD / BK)  // 64 k-tiles
#define SL 4096       // seq len
#define BB 4          // batch
#define NTHR 512      // 8 waves/block for latency hiding
#define XSTR 68       // LDS tile stride (64 + 4 pad)

// numpy SIMD float32 exp (P/Q rational — locked by R26/R27)
__device__ __forceinline__ float np_expf(float x) {
    const float LOG2E = 1.442695040888963407359924681001892137f;
    const float MAGIC = 0x1.800000p+23f;
    const float C1 = -6.93145752e-1f;
    const float C2 = -1.42860677e-6f;
    float q = __fmul_rn(x, LOG2E);
    q = __fadd_rn(q, MAGIC);
    q = __fsub_rn(q, MAGIC);
    x = __fmaf_rn(q, C1, x);
    x = __fmaf_rn(q, C2, x);
    float num = __fmaf_rn(5.082762527590693718096e-04f, x, 6.757896990527504603057e-03f);
    num = __fmaf_rn(num, x, 5.114512081637298353406e-02f);
    num = __fmaf_rn(num, x, 2.473615434895520810817e-01f);
    num = __fmaf_rn(num, x, 7.257664613233124478488e-01f);
    num = __fmaf_rn(num, x, 9.999999999980870924916e-01f);
    float den = __fmaf_rn(2.159509375685829852307e-02f, x, -2.742335390411667452936e-01f);
    den = __fmaf_rn(den, x, 1.0f);
    const float quot = __fdiv_rn(num, den);
    const int qi = (int)q;
    const float sc = __uint_as_float((unsigned int)(127 + qi) << 23);
    return __fmul_rn(quot, sc);
}

// GEMM arithmetic (LOCKED, bit-exact vs np ref): OpenBLAS skylakex sgemm,
// K=2048 -> chunks [320 x5, 224, 224], fold boundaries kt+1 in
// {10,20,30,40,50,57,64}; microkernel = 2 accumulator banks, QUADS
// assignment bank=(k>>2)&1, TREE combine (c0+c1), one f32 add into C.
__device__ __forceinline__ bool is_fold(int kt1) {
    return kt1 == 10 || kt1 == 20 || kt1 == 30 || kt1 == 40 ||
           kt1 == 50 || kt1 == 57 || kt1 == 64;
}

__global__ __launch_bounds__(NTHR) void moe_gate_main(
    const float* __restrict__ X, const float* __restrict__ W,
    float* __restrict__ out, float* __restrict__ ws_cnt, float* __restrict__ ws_ssum)
{
    __shared__ float Xs[2][BK * XSTR];
    __shared__ float Wsh[2][BK * XSTR];
    __shared__ float Ls[BM * XSTR];
    __shared__ float cnt[EE];

    const int tid  = threadIdx.x;
    const int row0 = blockIdx.x * BM;
    const int tr   = tid >> 4;   // 0..31 -> rows 2tr, 2tr+1
    const int tc   = tid & 15;   // 0..15 -> cols 4tc..4tc+3

    float tot[2][4];      // C across K-chunks
    float ch[2][2][4];    // 2 banks x (2 rows x 4 cols)
#pragma unroll
    for (int i = 0; i < 2; ++i)
#pragma unroll
        for (int j = 0; j < 4; ++j) {
            tot[i][j] = 0.f; ch[0][i][j] = 0.f; ch[1][i][j] = 0.f;
        }

    if (tid < EE) cnt[tid] = 0.f;

    // hoisted per-thread staging pointers + LDS destinations (4 each)
    const float* xptr[4]; int xdst[4];
    const float* wptr[4]; int wdst[4];
#pragma unroll
    for (int j = 0; j < 4; ++j) {          // 64r x 32k = 2048 / 512 = 4 each
        const int el = j * NTHR + tid;
        const int r = el >> 5, kk = el & 31;
        xptr[j] = X + (size_t)(row0 + r) * DD + kk;
        xdst[j] = kk * XSTR + r;
        wptr[j] = W + (size_t)r * DD + kk;
        wdst[j] = kk * XSTR + r;
    }

    float xr[4], wr[4];
#pragma unroll
    for (int j = 0; j < 4; ++j) { xr[j] = *xptr[j]; xptr[j] += BK; }
#pragma unroll
    for (int j = 0; j < 4; ++j) { wr[j] = *wptr[j]; wptr[j] += BK; }
#pragma unroll
    for (int j = 0; j < 4; ++j) Xs[0][xdst[j]] = xr[j];
#pragma unroll
    for (int j = 0; j < 4; ++j) Wsh[0][wdst[j]] = wr[j];

    for (int kt = 0; kt < NT; ++kt) {
        __syncthreads();
        const int cur = kt & 1;
        if (kt + 1 < NT) {   // issue next-tile loads early
#pragma unroll
            for (int j = 0; j < 4; ++j) { xr[j] = *xptr[j]; xptr[j] += BK; }
#pragma unroll
            for (int j = 0; j < 4; ++j) { wr[j] = *wptr[j]; wptr[j] += BK; }
        }
        // 2-bank QUADS FMA chains; (kk>>2)&1 compile-time after unroll
#pragma unroll
        for (int kk = 0; kk < BK; ++kk) {
            const int p = (kk >> 2) & 1;
            const float2 a = *(const float2*)&Xs[cur][kk * XSTR + 2 * tr];
            const float4 b = *(const float4*)&Wsh[cur][kk * XSTR + 4 * tc];
            ch[p][0][0] = __fmaf_rn(a.x, b.x, ch[p][0][0]);
            ch[p][0][1] = __fmaf_rn(a.x, b.y, ch[p][0][1]);
            ch[p][0][2] = __fmaf_rn(a.x, b.z, ch[p][0][2]);
            ch[p][0][3] = __fmaf_rn(a.x, b.w, ch[p][0][3]);
            ch[p][1][0] = __fmaf_rn(a.y, b.x, ch[p][1][0]);
            ch[p][1][1] = __fmaf_rn(a.y, b.y, ch[p][1][1]);
            ch[p][1][2] = __fmaf_rn(a.y, b.z, ch[p][1][2]);
            ch[p][1][3] = __fmaf_rn(a.y, b.w, ch[p][1][3]);
        }
        if (is_fold(kt + 1)) {
#pragma unroll
            for (int i = 0; i < 2; ++i)
#pragma unroll
                for (int j = 0; j < 4; ++j) {
                    const float c2 = __fadd_rn(ch[0][i][j], ch[1][i][j]);
                    tot[i][j] = __fadd_rn(tot[i][j], c2);
                    ch[0][i][j] = 0.f; ch[1][i][j] = 0.f;
                }
        }
        if (kt + 1 < NT) {
#pragma unroll
            for (int j = 0; j < 4; ++j) Xs[cur ^ 1][xdst[j]] = xr[j];
#pragma unroll
            for (int j = 0; j < 4; ++j) Wsh[cur ^ 1][wdst[j]] = wr[j];
        }
    }

    // logits -> LDS
#pragma unroll
    for (int i = 0; i < 2; ++i) {
        float4 v; v.x = tot[i][0]; v.y = tot[i][1]; v.z = tot[i][2]; v.w = tot[i][3];
        *(float4*)&Ls[(2 * tr + i) * XSTR + 4 * tc] = v;
    }
    __syncthreads();

    if (tid < BM) {
        const int r = tid;
        float l[EE];
#pragma unroll
        for (int q = 0; q < 16; ++q) {
            const float4 v = *(const float4*)&Ls[r * XSTR + 4 * q];
            l[4 * q] = v.x; l[4 * q + 1] = v.y; l[4 * q + 2] = v.z; l[4 * q + 3] = v.w;
        }
        float m = l[0];
#pragma unroll
        for (int e = 1; e < EE; ++e) m = fmaxf(m, l[e]);

        // u = np.exp(l - m) (P/Q rational)
        float u[EE];
#pragma unroll
        for (int e = 0; e < EE; ++e) u[e] = np_expf(__fsub_rn(l[e], m));

        // z = numpy pairwise (8 accumulators, ascending chunks,
        // ((r0+r1)+(r2+r3)) + ((r4+r5)+(r6+r7)))
        float rr[8];
#pragma unroll
        for (int j = 0; j < 8; ++j) rr[j] = u[j];
#pragma unroll
        for (int c = 1; c < 8; ++c)
#pragma unroll
            for (int j = 0; j < 8; ++j) rr[j] = __fadd_rn(rr[j], u[8 * c + j]);
        const float z = __fadd_rn(
            __fadd_rn(__fadd_rn(rr[0], rr[1]), __fadd_rn(rr[2], rr[3])),
            __fadd_rn(__fadd_rn(rr[4], rr[5]), __fadd_rn(rr[6], rr[7])));

        float s[EE];
#pragma unroll
        for (int e = 0; e < EE; ++e) s[e] = __fdiv_rn(u[e], z);

        // top-8 on f32 scores: value desc, index ASC on exact ties
        float pv = 3.4e38f; int pi = -1;
        float wk[KTOP]; int ti[KTOP]; float wsum = 0.f;
#pragma unroll
        for (int k = 0; k < KTOP; ++k) {
            float best = -3.4e38f; int bi = 0;
#pragma unroll
            for (int e = 0; e < EE; ++e) {
                const bool elig   = (s[e] < pv) || ((s[e] == pv) && (e > pi));
                const bool better = elig && (s[e] > best);
                best = better ? s[e] : best;
                bi   = better ? e    : bi;
            }
            wk[k] = best; ti[k] = bi; wsum = __fadd_rn(wsum, best);
            pv = best; pi = bi;
        }
        const float den = __fadd_rn(wsum, 1e-20f);

        const size_t t = (size_t)row0 + r;
        float4 o0, o1;
        o0.x = (float)ti[0]; o0.y = (float)ti[1]; o0.z = (float)ti[2]; o0.w = (float)ti[3];
        o1.x = (float)ti[4]; o1.y = (float)ti[5]; o1.z = (float)ti[6]; o1.w = (float)ti[7];
        *(float4*)&out[t * 8]     = o0;
        *(float4*)&out[t * 8 + 4] = o1;
        float* outw = out + (size_t)TT * KTOP;
        o0.x = __fdiv_rn(wk[0], den); o0.y = __fdiv_rn(wk[1], den);
        o0.z = __fdiv_rn(wk[2], den); o0.w = __fdiv_rn(wk[3], den);
        o1.x = __fdiv_rn(wk[4], den); o1.y = __fdiv_rn(wk[5], den);
        o1.z = __fdiv_rn(wk[6], den); o1.w = __fdiv_rn(wk[7], den);
        *(float4*)&outw[t * 8]     = o0;
        *(float4*)&outw[t * 8 + 4] = o1;

#pragma unroll
        for (int k = 0; k < KTOP; ++k) atomicAdd(&cnt[ti[k]], 1.f);

        // scores back to LDS for column sums
#pragma unroll
        for (int q = 0; q < 16; ++q) {
            float4 v;
            v.x = s[4 * q]; v.y = s[4 * q + 1]; v.z = s[4 * q + 2]; v.w = s[4 * q + 3];
            *(float4*)&Ls[r * XSTR + 4 * q] = v;
        }
    }
    __syncthreads();

    if (tid < EE) {
        const int e = tid;
        float cs = 0.f;
#pragma unroll
        for (int r2 = 0; r2 < BM; ++r2) cs += Ls[r2 * XSTR + e];
        const int b = row0 / SL;
        atomicAdd(&ws_ssum[b * EE + e], cs);
        atomicAdd(&ws_cnt[b * EE + e], cnt[e]);
    }
}

__global__ void moe_gate_aux(const float* __restrict__ ws_cnt,
                             const float* __restrict__ ws_ssum,
                             float* __restrict__ out_aux)
{
    __shared__ float red[4];
    const int tid = threadIdx.x;  // 256 = B*E cells
    float v = ws_cnt[tid] * ws_ssum[tid];
#pragma unroll
    for (int m = 32; m; m >>= 1) v += __shfl_xor(v, m, 64);
    if ((tid & 63) == 0) red[tid >> 6] = v;
    __syncthreads();
    if (tid == 0) {
        const float tot = red[0] + red[1] + red[2] + red[3];
        // aux = ALPHA * (1/B) * sum_{b,e} (cnt/(S*K/E)) * (ssum/S)
        out_aux[0] = tot * (1e-3f / ((float)BB * 512.f * (float)SL));
    }
}

extern "C" void kernel_launch(void* const* d_in, const int* in_sizes, int n_in,
                              void* d_out, int out_size, void* d_ws, size_t ws_size,
                              hipStream_t stream)
{
    const float* X = (const float*)d_in[0];
    const float* W = (const float*)d_in[1];
    float* out  = (float*)d_out;
    float* cnt  = (float*)d_ws;
    float* ssum = cnt + BB * EE;
    hipMemsetAsync(d_ws, 0, 2 * BB * EE * sizeof(float), stream);
    moe_gate_main<<<TT / BM, NTHR, 0, stream>>>(X, W, out, cnt, ssum);
    moe_gate_aux<<<1, 256, 0, stream>>>(cnt, ssum, out + (size_t)2 * TT * KTOP);
}